// Round 10
// baseline (129.678 us; speedup 1.0000x reference)
//
#include <hip/hip_runtime.h>
#include <math.h>

#define NN 102400
#define D 256
#define B 2048

typedef __bf16 bf16x8 __attribute__((ext_vector_type(8)));
typedef float f32x4 __attribute__((ext_vector_type(4)));

// K0: seg_start[b] = lower_bound(seg_ids, b); seg_start[B] = NN
__global__ void k_bounds(const int* __restrict__ seg, int* __restrict__ seg_start) {
    int b = blockIdx.x * blockDim.x + threadIdx.x;
    if (b > B) return;
    int lo = 0, hi = NN;
    while (lo < hi) { int mid = (lo + hi) >> 1; if (seg[mid] < b) lo = mid + 1; else hi = mid; }
    seg_start[b] = lo;
}

// K1: anchor (segment mean) -> out[:, 256:512]
__global__ void k_anchor(const float* __restrict__ ifeat, const int* __restrict__ seg_start,
                         float* __restrict__ out) {
    int b = blockIdx.x;
    int t = threadIdx.x; // 256 threads, thread = column
    int s = seg_start[b], e = seg_start[b + 1];
    float a0 = 0.f, a1 = 0.f, a2 = 0.f, a3 = 0.f;
    int i = s;
    for (; i + 4 <= e; i += 4) {
        a0 += ifeat[(size_t)(i + 0) * D + t];
        a1 += ifeat[(size_t)(i + 1) * D + t];
        a2 += ifeat[(size_t)(i + 2) * D + t];
        a3 += ifeat[(size_t)(i + 3) * D + t];
    }
    for (; i < e; ++i) a0 += ifeat[(size_t)i * D + t];
    float sum = (a0 + a1) + (a2 + a3);
    int cnt = e - s;
    float inv = 1.0f / (float)(cnt > 0 ? cnt : 1);
    out[(size_t)b * 512 + 256 + t] = sum * inv;
}

// K2: feat_v = anchor @ Wv^T + bv, 16 segments per block
__global__ void k_featv(const float* __restrict__ out, const float* __restrict__ Wv,
                        const float* __restrict__ bv, float* __restrict__ feat_v) {
    __shared__ float anc[16][D];
    int b0 = blockIdx.x * 16;
    int t = threadIdx.x; // 256, thread = output column j
#pragma unroll
    for (int r = 0; r < 16; ++r) anc[r][t] = out[(size_t)(b0 + r) * 512 + 256 + t];
    __syncthreads();
    float acc[16];
#pragma unroll
    for (int s = 0; s < 16; ++s) acc[s] = 0.f;
    const float* wrow = Wv + (size_t)t * D;
    for (int k = 0; k < D; k += 4) {
        float4 w = *(const float4*)(wrow + k);
#pragma unroll
        for (int s = 0; s < 16; ++s) {
            acc[s] += anc[s][k] * w.x + anc[s][k + 1] * w.y
                    + anc[s][k + 2] * w.z + anc[s][k + 3] * w.w;
        }
    }
    float bj = bv[t];
#pragma unroll
    for (int s = 0; s < 16; ++s) feat_v[(size_t)(b0 + s) * D + t] = acc[s] + bj;
}

// K3 (MFMA, single-pass full-Wu): e[n] = we . sigmoid(bf16(ifeat[n]) @ bf16(Wu)^T + fv)
// 256 blocks x 1024 thr (16 waves). FULL Wu staged once into 128 KB LDS (bf16,
// swizzled) -> 1 block/CU, 16 waves/CU. vs R9's j-split: A-traffic halves
// (no duplicate ifeat stream). Rolled `#pragma unroll 1` chunk loop, 1-deep named
// prefetch (R8 lesson: straight-line bodies -> load hoisting -> spill). acc
// a0..a15 are MFMA C/D operands -> AGPRs (don't count vs 128 arch-VGPR cap).
__global__ __launch_bounds__(1024, 4)
void k_attn_e_mfma(const float* __restrict__ ifeat, const float* __restrict__ Wu,
                   const float* __restrict__ feat_v, const float* __restrict__ we,
                   const int* __restrict__ seg_ids, float* __restrict__ e_out) {
    __shared__ __bf16 Bs[256 * 256];   // 128 KB; row j stride 512 B; byte ^= (j&7)<<4

    int tx = threadIdx.x;
    int lane = tx & 63;
    int w = tx >> 6;                   // 0..15
    int ln15 = lane & 15;
    int lg = lane >> 4;

    // ---- stage full Wu: thread -> (row jl=tx>>2, k-quarter kh=tx&3), 64 elems ----
    {
        int jl = tx >> 2, kh = tx & 3;
        const float* wp = Wu + (size_t)jl * D + kh * 64;
        char* rowp = (char*)Bs + jl * 512;
        int sw = (jl & 7) << 4;
#pragma unroll
        for (int q = 0; q < 8; ++q) {
            float4 b0 = *(const float4*)(wp + q * 8);
            float4 b1 = *(const float4*)(wp + q * 8 + 4);
            bf16x8 v;
            v[0] = (__bf16)b0.x; v[1] = (__bf16)b0.y; v[2] = (__bf16)b0.z; v[3] = (__bf16)b0.w;
            v[4] = (__bf16)b1.x; v[5] = (__bf16)b1.y; v[6] = (__bf16)b1.z; v[7] = (__bf16)b1.w;
            *(bf16x8*)(rowp + ((kh * 128 + q * 16) ^ sw)) = v;
        }
    }
    __syncthreads();

    int swr = (ln15 & 7) << 4;               // read swizzle (LDS row = ct*16+ln15, row&7==ln15&7)
    int klo = lg * 16;                       // k-byte offset of this lane-group's 8 elems
    const char* bbase = (const char*)Bs + ln15 * 512;
    const float* feph = feat_v + ln15;
    const float* weh  = we + ln15;

    int wgid = blockIdx.x * 16 + w;          // 0..4095

    for (int item = wgid; item < NN / 16; item += 4096) {
        int nb = item * 16;
        const float* ap = ifeat + (size_t)(nb + ln15) * D + lg * 8;

        f32x4 a0 = (f32x4){0.f,0.f,0.f,0.f}, a1 = a0, a2 = a0, a3 = a0,
              a4 = a0, a5 = a0, a6 = a0, a7 = a0,
              a8 = a0, a9 = a0, a10 = a0, a11 = a0,
              a12 = a0, a13 = a0, a14 = a0, a15 = a0;

        // rolled chunk loop, 1-deep named-register prefetch (all-static names)
        float4 xc = *(const float4*)(ap);
        float4 yc = *(const float4*)(ap + 4);
#pragma unroll 1
        for (int ch = 0; ch < 8; ++ch) {
            int nx = ((ch + 1) & 7) * 32;              // wrap: last iter re-reads ch0 (in-bounds)
            float4 xn = *(const float4*)(ap + nx);
            float4 yn = *(const float4*)(ap + nx + 4);
            bf16x8 af;
            af[0] = (__bf16)xc.x; af[1] = (__bf16)xc.y; af[2] = (__bf16)xc.z; af[3] = (__bf16)xc.w;
            af[4] = (__bf16)yc.x; af[5] = (__bf16)yc.y; af[6] = (__bf16)yc.z; af[7] = (__bf16)yc.w;
            int kb = (ch * 64 + klo) ^ swr;
            a0  = __builtin_amdgcn_mfma_f32_16x16x32_bf16(af, *(const bf16x8*)(bbase +  0 * 8192 + kb), a0,  0, 0, 0);
            a1  = __builtin_amdgcn_mfma_f32_16x16x32_bf16(af, *(const bf16x8*)(bbase +  1 * 8192 + kb), a1,  0, 0, 0);
            a2  = __builtin_amdgcn_mfma_f32_16x16x32_bf16(af, *(const bf16x8*)(bbase +  2 * 8192 + kb), a2,  0, 0, 0);
            a3  = __builtin_amdgcn_mfma_f32_16x16x32_bf16(af, *(const bf16x8*)(bbase +  3 * 8192 + kb), a3,  0, 0, 0);
            a4  = __builtin_amdgcn_mfma_f32_16x16x32_bf16(af, *(const bf16x8*)(bbase +  4 * 8192 + kb), a4,  0, 0, 0);
            a5  = __builtin_amdgcn_mfma_f32_16x16x32_bf16(af, *(const bf16x8*)(bbase +  5 * 8192 + kb), a5,  0, 0, 0);
            a6  = __builtin_amdgcn_mfma_f32_16x16x32_bf16(af, *(const bf16x8*)(bbase +  6 * 8192 + kb), a6,  0, 0, 0);
            a7  = __builtin_amdgcn_mfma_f32_16x16x32_bf16(af, *(const bf16x8*)(bbase +  7 * 8192 + kb), a7,  0, 0, 0);
            a8  = __builtin_amdgcn_mfma_f32_16x16x32_bf16(af, *(const bf16x8*)(bbase +  8 * 8192 + kb), a8,  0, 0, 0);
            a9  = __builtin_amdgcn_mfma_f32_16x16x32_bf16(af, *(const bf16x8*)(bbase +  9 * 8192 + kb), a9,  0, 0, 0);
            a10 = __builtin_amdgcn_mfma_f32_16x16x32_bf16(af, *(const bf16x8*)(bbase + 10 * 8192 + kb), a10, 0, 0, 0);
            a11 = __builtin_amdgcn_mfma_f32_16x16x32_bf16(af, *(const bf16x8*)(bbase + 11 * 8192 + kb), a11, 0, 0, 0);
            a12 = __builtin_amdgcn_mfma_f32_16x16x32_bf16(af, *(const bf16x8*)(bbase + 12 * 8192 + kb), a12, 0, 0, 0);
            a13 = __builtin_amdgcn_mfma_f32_16x16x32_bf16(af, *(const bf16x8*)(bbase + 13 * 8192 + kb), a13, 0, 0, 0);
            a14 = __builtin_amdgcn_mfma_f32_16x16x32_bf16(af, *(const bf16x8*)(bbase + 14 * 8192 + kb), a14, 0, 0, 0);
            a15 = __builtin_amdgcn_mfma_f32_16x16x32_bf16(af, *(const bf16x8*)(bbase + 15 * 8192 + kb), a15, 0, 0, 0);
            xc = xn; yc = yn;
        }

        // ---- epilogue: u = acc + feat_v[seg[row]][col]; part += we*sigmoid(u) ----
        int r0 = nb + lg * 4;
        const float* fp0 = feph + (size_t)seg_ids[r0 + 0] * D;
        const float* fp1 = feph + (size_t)seg_ids[r0 + 1] * D;
        const float* fp2 = feph + (size_t)seg_ids[r0 + 2] * D;
        const float* fp3 = feph + (size_t)seg_ids[r0 + 3] * D;
        float part0 = 0.f, part1 = 0.f, part2 = 0.f, part3 = 0.f;

#define EPI(AC, CT) { \
    float w_ = weh[(CT) * 16]; \
    part0 += w_ / (1.f + __expf(-(AC[0] + fp0[(CT) * 16]))); \
    part1 += w_ / (1.f + __expf(-(AC[1] + fp1[(CT) * 16]))); \
    part2 += w_ / (1.f + __expf(-(AC[2] + fp2[(CT) * 16]))); \
    part3 += w_ / (1.f + __expf(-(AC[3] + fp3[(CT) * 16]))); }

        EPI(a0, 0)  EPI(a1, 1)  EPI(a2, 2)  EPI(a3, 3)
        EPI(a4, 4)  EPI(a5, 5)  EPI(a6, 6)  EPI(a7, 7)
        EPI(a8, 8)  EPI(a9, 9)  EPI(a10, 10) EPI(a11, 11)
        EPI(a12, 12) EPI(a13, 13) EPI(a14, 14) EPI(a15, 15)
#undef EPI

        // reduce over the 16 col-lanes
#pragma unroll
        for (int off = 8; off >= 1; off >>= 1) {
            part0 += __shfl_xor(part0, off, 64);
            part1 += __shfl_xor(part1, off, 64);
            part2 += __shfl_xor(part2, off, 64);
            part3 += __shfl_xor(part3, off, 64);
        }
        if (ln15 == 0) {
            float4 o = make_float4(part0, part1, part2, part3);
            *(float4*)&e_out[r0] = o;
        }
    }
}

// K4: segment softmax (max, denom) + alpha-weighted segment sum -> out[:, 0:256]
// Phase 3 unrolled x4: 4 row-loads in flight.
__global__ void k_softmax_rst(const float* __restrict__ ifeat, const int* __restrict__ seg_start,
                              const float* __restrict__ e, float* __restrict__ out) {
    int b = blockIdx.x;
    int t = threadIdx.x; // 256
    int s = seg_start[b], en = seg_start[b + 1];
    float m = -1e30f;
    for (int i = s + t; i < en; i += 256) m = fmaxf(m, e[i]);
#pragma unroll
    for (int off = 32; off >= 1; off >>= 1) m = fmaxf(m, __shfl_xor(m, off, 64));
    __shared__ float red[4];
    if ((t & 63) == 0) red[t >> 6] = m;
    __syncthreads();
    float mall = fmaxf(fmaxf(red[0], red[1]), fmaxf(red[2], red[3]));
    float dsum = 0.f;
    for (int i = s + t; i < en; i += 256) dsum += __expf(e[i] - mall);
#pragma unroll
    for (int off = 32; off >= 1; off >>= 1) dsum += __shfl_xor(dsum, off, 64);
    __shared__ float red2[4];
    if ((t & 63) == 0) red2[t >> 6] = dsum;
    __syncthreads();
    float denom = red2[0] + red2[1] + red2[2] + red2[3];
    float invd = (en > s) ? 1.0f / denom : 0.f;
    float ac0 = 0.f, ac1 = 0.f, ac2 = 0.f, ac3 = 0.f;
    int i = s;
    for (; i + 4 <= en; i += 4) {
        float al0 = __expf(e[i + 0] - mall) * invd;
        float al1 = __expf(e[i + 1] - mall) * invd;
        float al2 = __expf(e[i + 2] - mall) * invd;
        float al3 = __expf(e[i + 3] - mall) * invd;
        ac0 += ifeat[(size_t)(i + 0) * D + t] * al0;
        ac1 += ifeat[(size_t)(i + 1) * D + t] * al1;
        ac2 += ifeat[(size_t)(i + 2) * D + t] * al2;
        ac3 += ifeat[(size_t)(i + 3) * D + t] * al3;
    }
    for (; i < en; ++i) {
        float al = __expf(e[i] - mall) * invd;
        ac0 += ifeat[(size_t)i * D + t] * al;
    }
    out[(size_t)b * 512 + t] = (ac0 + ac1) + (ac2 + ac3);
}

extern "C" void kernel_launch(void* const* d_in, const int* in_sizes, int n_in,
                              void* d_out, int out_size, void* d_ws, size_t ws_size,
                              hipStream_t stream) {
    const float* ifeat = (const float*)d_in[0];
    const float* Wu    = (const float*)d_in[1];
    const float* Wv    = (const float*)d_in[2];
    const float* bv    = (const float*)d_in[3];
    const float* we    = (const float*)d_in[4];
    const int*   seg   = (const int*)d_in[5];
    float* out = (float*)d_out;

    char* ws = (char*)d_ws;
    int*   seg_start = (int*)ws;                                   // (B+1) ints
    float* feat_v    = (float*)(ws + 16384);                       // B*D floats (2 MB)
    float* e_buf     = (float*)(ws + 16384 + (size_t)B * D * 4);   // NN floats (400 KB)

    k_bounds<<<(B + 1 + 255) / 256, 256, 0, stream>>>(seg, seg_start);
    k_anchor<<<B, 256, 0, stream>>>(ifeat, seg_start, out);
    k_featv<<<B / 16, 256, 0, stream>>>(out, Wv, bv, feat_v);
    k_attn_e_mfma<<<256, 1024, 0, stream>>>(ifeat, Wu, feat_v, we, seg, e_buf);
    k_softmax_rst<<<B, 256, 0, stream>>>(ifeat, seg_start, e_buf, out);
}

// Round 11
// 128.450 us; speedup vs baseline: 1.0096x; 1.0096x over previous
//
#include <hip/hip_runtime.h>
#include <math.h>

#define NN 102400
#define D 256
#define B 2048

typedef __bf16 bf16x8 __attribute__((ext_vector_type(8)));
typedef float f32x4 __attribute__((ext_vector_type(4)));

// K0: seg_start[b] = lower_bound(seg_ids, b); seg_start[B] = NN
__global__ void k_bounds(const int* __restrict__ seg, int* __restrict__ seg_start) {
    int b = blockIdx.x * blockDim.x + threadIdx.x;
    if (b > B) return;
    int lo = 0, hi = NN;
    while (lo < hi) { int mid = (lo + hi) >> 1; if (seg[mid] < b) lo = mid + 1; else hi = mid; }
    seg_start[b] = lo;
}

// K1: anchor (segment mean) -> out[:, 256:512]
// Wave-per-row float4 (G13): wave w handles rows s+w, s+w+4, ...; lane l = cols [4l,4l+4).
// One coalesced 1 KB load per row per wave, 4 rows in flight; cross-wave LDS reduce.
__global__ void k_anchor(const float* __restrict__ ifeat, const int* __restrict__ seg_start,
                         float* __restrict__ out) {
    int b = blockIdx.x;
    int t = threadIdx.x;           // 256
    int w = t >> 6, l = t & 63;
    int s = seg_start[b], e = seg_start[b + 1];
    float4 acc = make_float4(0.f, 0.f, 0.f, 0.f);
    for (int i = s + w; i < e; i += 4) {
        float4 v = *(const float4*)(ifeat + (size_t)i * D + l * 4);
        acc.x += v.x; acc.y += v.y; acc.z += v.z; acc.w += v.w;
    }
    __shared__ float red[4][256];
    *(float4*)&red[w][l * 4] = acc;
    __syncthreads();
    float sum = red[0][t] + red[1][t] + red[2][t] + red[3][t];
    int cnt = e - s;
    float inv = 1.0f / (float)(cnt > 0 ? cnt : 1);
    out[(size_t)b * 512 + 256 + t] = sum * inv;
}

// K2: feat_v = anchor @ Wv^T + bv, 16 segments per block
__global__ void k_featv(const float* __restrict__ out, const float* __restrict__ Wv,
                        const float* __restrict__ bv, float* __restrict__ feat_v) {
    __shared__ float anc[16][D];
    int b0 = blockIdx.x * 16;
    int t = threadIdx.x; // 256, thread = output column j
#pragma unroll
    for (int r = 0; r < 16; ++r) anc[r][t] = out[(size_t)(b0 + r) * 512 + 256 + t];
    __syncthreads();
    float acc[16];
#pragma unroll
    for (int s = 0; s < 16; ++s) acc[s] = 0.f;
    const float* wrow = Wv + (size_t)t * D;
    for (int k = 0; k < D; k += 4) {
        float4 w = *(const float4*)(wrow + k);
#pragma unroll
        for (int s = 0; s < 16; ++s) {
            acc[s] += anc[s][k] * w.x + anc[s][k + 1] * w.y
                    + anc[s][k + 2] * w.z + anc[s][k + 3] * w.w;
        }
    }
    float bj = bv[t];
#pragma unroll
    for (int s = 0; s < 16; ++s) feat_v[(size_t)(b0 + s) * D + t] = acc[s] + bj;
}

// K3 (MFMA, single-pass full-Wu): e[n] = we . sigmoid(bf16(ifeat[n]) @ bf16(Wu)^T + fv)
// 256 blocks x 1024 thr (16 waves). FULL Wu staged once into 128 KB LDS (bf16,
// swizzled) -> 1 block/CU, 16 waves/CU. Rolled `#pragma unroll 1` chunk loop,
// 1-deep named prefetch (R8 lesson). acc a0..a15 -> AGPR side of unified file.
// R10 lesson: binding resource is the LDS read pipe (1 ds_read_b128 per MFMA);
// j-split vs full-Wu is perf-neutral. UNCHANGED from R10 for attribution.
__global__ __launch_bounds__(1024, 4)
void k_attn_e_mfma(const float* __restrict__ ifeat, const float* __restrict__ Wu,
                   const float* __restrict__ feat_v, const float* __restrict__ we,
                   const int* __restrict__ seg_ids, float* __restrict__ e_out) {
    __shared__ __bf16 Bs[256 * 256];   // 128 KB; row j stride 512 B; byte ^= (j&7)<<4

    int tx = threadIdx.x;
    int lane = tx & 63;
    int w = tx >> 6;                   // 0..15
    int ln15 = lane & 15;
    int lg = lane >> 4;

    // ---- stage full Wu: thread -> (row jl=tx>>2, k-quarter kh=tx&3), 64 elems ----
    {
        int jl = tx >> 2, kh = tx & 3;
        const float* wp = Wu + (size_t)jl * D + kh * 64;
        char* rowp = (char*)Bs + jl * 512;
        int sw = (jl & 7) << 4;
#pragma unroll
        for (int q = 0; q < 8; ++q) {
            float4 b0 = *(const float4*)(wp + q * 8);
            float4 b1 = *(const float4*)(wp + q * 8 + 4);
            bf16x8 v;
            v[0] = (__bf16)b0.x; v[1] = (__bf16)b0.y; v[2] = (__bf16)b0.z; v[3] = (__bf16)b0.w;
            v[4] = (__bf16)b1.x; v[5] = (__bf16)b1.y; v[6] = (__bf16)b1.z; v[7] = (__bf16)b1.w;
            *(bf16x8*)(rowp + ((kh * 128 + q * 16) ^ sw)) = v;
        }
    }
    __syncthreads();

    int swr = (ln15 & 7) << 4;               // read swizzle (LDS row = ct*16+ln15, row&7==ln15&7)
    int klo = lg * 16;                       // k-byte offset of this lane-group's 8 elems
    const char* bbase = (const char*)Bs + ln15 * 512;
    const float* feph = feat_v + ln15;
    const float* weh  = we + ln15;

    int wgid = blockIdx.x * 16 + w;          // 0..4095

    for (int item = wgid; item < NN / 16; item += 4096) {
        int nb = item * 16;
        const float* ap = ifeat + (size_t)(nb + ln15) * D + lg * 8;

        f32x4 a0 = (f32x4){0.f,0.f,0.f,0.f}, a1 = a0, a2 = a0, a3 = a0,
              a4 = a0, a5 = a0, a6 = a0, a7 = a0,
              a8 = a0, a9 = a0, a10 = a0, a11 = a0,
              a12 = a0, a13 = a0, a14 = a0, a15 = a0;

        // rolled chunk loop, 1-deep named-register prefetch (all-static names)
        float4 xc = *(const float4*)(ap);
        float4 yc = *(const float4*)(ap + 4);
#pragma unroll 1
        for (int ch = 0; ch < 8; ++ch) {
            int nx = ((ch + 1) & 7) * 32;              // wrap: last iter re-reads ch0 (in-bounds)
            float4 xn = *(const float4*)(ap + nx);
            float4 yn = *(const float4*)(ap + nx + 4);
            bf16x8 af;
            af[0] = (__bf16)xc.x; af[1] = (__bf16)xc.y; af[2] = (__bf16)xc.z; af[3] = (__bf16)xc.w;
            af[4] = (__bf16)yc.x; af[5] = (__bf16)yc.y; af[6] = (__bf16)yc.z; af[7] = (__bf16)yc.w;
            int kb = (ch * 64 + klo) ^ swr;
            a0  = __builtin_amdgcn_mfma_f32_16x16x32_bf16(af, *(const bf16x8*)(bbase +  0 * 8192 + kb), a0,  0, 0, 0);
            a1  = __builtin_amdgcn_mfma_f32_16x16x32_bf16(af, *(const bf16x8*)(bbase +  1 * 8192 + kb), a1,  0, 0, 0);
            a2  = __builtin_amdgcn_mfma_f32_16x16x32_bf16(af, *(const bf16x8*)(bbase +  2 * 8192 + kb), a2,  0, 0, 0);
            a3  = __builtin_amdgcn_mfma_f32_16x16x32_bf16(af, *(const bf16x8*)(bbase +  3 * 8192 + kb), a3,  0, 0, 0);
            a4  = __builtin_amdgcn_mfma_f32_16x16x32_bf16(af, *(const bf16x8*)(bbase +  4 * 8192 + kb), a4,  0, 0, 0);
            a5  = __builtin_amdgcn_mfma_f32_16x16x32_bf16(af, *(const bf16x8*)(bbase +  5 * 8192 + kb), a5,  0, 0, 0);
            a6  = __builtin_amdgcn_mfma_f32_16x16x32_bf16(af, *(const bf16x8*)(bbase +  6 * 8192 + kb), a6,  0, 0, 0);
            a7  = __builtin_amdgcn_mfma_f32_16x16x32_bf16(af, *(const bf16x8*)(bbase +  7 * 8192 + kb), a7,  0, 0, 0);
            a8  = __builtin_amdgcn_mfma_f32_16x16x32_bf16(af, *(const bf16x8*)(bbase +  8 * 8192 + kb), a8,  0, 0, 0);
            a9  = __builtin_amdgcn_mfma_f32_16x16x32_bf16(af, *(const bf16x8*)(bbase +  9 * 8192 + kb), a9,  0, 0, 0);
            a10 = __builtin_amdgcn_mfma_f32_16x16x32_bf16(af, *(const bf16x8*)(bbase + 10 * 8192 + kb), a10, 0, 0, 0);
            a11 = __builtin_amdgcn_mfma_f32_16x16x32_bf16(af, *(const bf16x8*)(bbase + 11 * 8192 + kb), a11, 0, 0, 0);
            a12 = __builtin_amdgcn_mfma_f32_16x16x32_bf16(af, *(const bf16x8*)(bbase + 12 * 8192 + kb), a12, 0, 0, 0);
            a13 = __builtin_amdgcn_mfma_f32_16x16x32_bf16(af, *(const bf16x8*)(bbase + 13 * 8192 + kb), a13, 0, 0, 0);
            a14 = __builtin_amdgcn_mfma_f32_16x16x32_bf16(af, *(const bf16x8*)(bbase + 14 * 8192 + kb), a14, 0, 0, 0);
            a15 = __builtin_amdgcn_mfma_f32_16x16x32_bf16(af, *(const bf16x8*)(bbase + 15 * 8192 + kb), a15, 0, 0, 0);
            xc = xn; yc = yn;
        }

        // ---- epilogue: u = acc + feat_v[seg[row]][col]; part += we*sigmoid(u) ----
        int r0 = nb + lg * 4;
        const float* fp0 = feph + (size_t)seg_ids[r0 + 0] * D;
        const float* fp1 = feph + (size_t)seg_ids[r0 + 1] * D;
        const float* fp2 = feph + (size_t)seg_ids[r0 + 2] * D;
        const float* fp3 = feph + (size_t)seg_ids[r0 + 3] * D;
        float part0 = 0.f, part1 = 0.f, part2 = 0.f, part3 = 0.f;

#define EPI(AC, CT) { \
    float w_ = weh[(CT) * 16]; \
    part0 += w_ / (1.f + __expf(-(AC[0] + fp0[(CT) * 16]))); \
    part1 += w_ / (1.f + __expf(-(AC[1] + fp1[(CT) * 16]))); \
    part2 += w_ / (1.f + __expf(-(AC[2] + fp2[(CT) * 16]))); \
    part3 += w_ / (1.f + __expf(-(AC[3] + fp3[(CT) * 16]))); }

        EPI(a0, 0)  EPI(a1, 1)  EPI(a2, 2)  EPI(a3, 3)
        EPI(a4, 4)  EPI(a5, 5)  EPI(a6, 6)  EPI(a7, 7)
        EPI(a8, 8)  EPI(a9, 9)  EPI(a10, 10) EPI(a11, 11)
        EPI(a12, 12) EPI(a13, 13) EPI(a14, 14) EPI(a15, 15)
#undef EPI

        // reduce over the 16 col-lanes
#pragma unroll
        for (int off = 8; off >= 1; off >>= 1) {
            part0 += __shfl_xor(part0, off, 64);
            part1 += __shfl_xor(part1, off, 64);
            part2 += __shfl_xor(part2, off, 64);
            part3 += __shfl_xor(part3, off, 64);
        }
        if (ln15 == 0) {
            float4 o = make_float4(part0, part1, part2, part3);
            *(float4*)&e_out[r0] = o;
        }
    }
}

// K4: segment softmax + alpha-weighted segment sum -> out[:, 0:256]
// Phase 3 wave-per-row float4 (G13): wave w rows s+w,s+w+4,...; lane l cols [4l,4l+4).
// alpha from broadcast e[i] load; per-thread float4 acc; cross-wave LDS reduce.
__global__ void k_softmax_rst(const float* __restrict__ ifeat, const int* __restrict__ seg_start,
                              const float* __restrict__ e, float* __restrict__ out) {
    int b = blockIdx.x;
    int t = threadIdx.x; // 256
    int w = t >> 6, l = t & 63;
    int s = seg_start[b], en = seg_start[b + 1];
    float m = -1e30f;
    for (int i = s + t; i < en; i += 256) m = fmaxf(m, e[i]);
#pragma unroll
    for (int off = 32; off >= 1; off >>= 1) m = fmaxf(m, __shfl_xor(m, off, 64));
    __shared__ float red[4];
    if ((t & 63) == 0) red[t >> 6] = m;
    __syncthreads();
    float mall = fmaxf(fmaxf(red[0], red[1]), fmaxf(red[2], red[3]));
    float dsum = 0.f;
    for (int i = s + t; i < en; i += 256) dsum += __expf(e[i] - mall);
#pragma unroll
    for (int off = 32; off >= 1; off >>= 1) dsum += __shfl_xor(dsum, off, 64);
    __shared__ float red2[4];
    if ((t & 63) == 0) red2[t >> 6] = dsum;
    __syncthreads();
    float denom = red2[0] + red2[1] + red2[2] + red2[3];
    float invd = (en > s) ? 1.0f / denom : 0.f;

    // phase 3: wave-per-row float4 weighted sum
    float4 acc = make_float4(0.f, 0.f, 0.f, 0.f);
    for (int i = s + w; i < en; i += 4) {
        float al = __expf(e[i] - mall) * invd;   // broadcast load + per-lane exp
        float4 v = *(const float4*)(ifeat + (size_t)i * D + l * 4);
        acc.x += v.x * al; acc.y += v.y * al; acc.z += v.z * al; acc.w += v.w * al;
    }
    __shared__ float red3[4][256];
    *(float4*)&red3[w][l * 4] = acc;
    __syncthreads();
    out[(size_t)b * 512 + t] = (red3[0][t] + red3[1][t]) + (red3[2][t] + red3[3][t]);
}

extern "C" void kernel_launch(void* const* d_in, const int* in_sizes, int n_in,
                              void* d_out, int out_size, void* d_ws, size_t ws_size,
                              hipStream_t stream) {
    const float* ifeat = (const float*)d_in[0];
    const float* Wu    = (const float*)d_in[1];
    const float* Wv    = (const float*)d_in[2];
    const float* bv    = (const float*)d_in[3];
    const float* we    = (const float*)d_in[4];
    const int*   seg   = (const int*)d_in[5];
    float* out = (float*)d_out;

    char* ws = (char*)d_ws;
    int*   seg_start = (int*)ws;                                   // (B+1) ints
    float* feat_v    = (float*)(ws + 16384);                       // B*D floats (2 MB)
    float* e_buf     = (float*)(ws + 16384 + (size_t)B * D * 4);   // NN floats (400 KB)

    k_bounds<<<(B + 1 + 255) / 256, 256, 0, stream>>>(seg, seg_start);
    k_anchor<<<B, 256, 0, stream>>>(ifeat, seg_start, out);
    k_featv<<<B / 16, 256, 0, stream>>>(out, Wv, bv, feat_v);
    k_attn_e_mfma<<<256, 1024, 0, stream>>>(ifeat, Wu, feat_v, we, seg, e_buf);
    k_softmax_rst<<<B, 256, 0, stream>>>(ifeat, seg_start, e_buf, out);
}

// Round 12
// 109.767 us; speedup vs baseline: 1.1814x; 1.1702x over previous
//
#include <hip/hip_runtime.h>
#include <math.h>

#define NN 102400
#define D 256
#define B 2048

typedef __bf16 bf16x8 __attribute__((ext_vector_type(8)));
typedef float f32x4 __attribute__((ext_vector_type(4)));

// K_prep: fused bounds + anchor + feat_v. 512 blocks x 256 thr; block p owns
// segments 4p..4p+3. Phase A: 5 threads binary-search seg_start. Phase B: wave w
// computes anchor of segment w (lane l = cols [4l,4l+4), 2-row unroll) -> LDS +
// out[:,256:512]. Phase C: feat_v = anc @ Wv^T + bv (thread = col, 4 segs).
__global__ __launch_bounds__(256)
void k_prep(const float* __restrict__ ifeat, const int* __restrict__ seg,
            const float* __restrict__ Wv, const float* __restrict__ bv,
            float* __restrict__ out, int* __restrict__ seg_start,
            float* __restrict__ feat_v) {
    __shared__ float anc[4][D];
    __shared__ int sb[5];
    int p = blockIdx.x, t = threadIdx.x;
    int b0 = p * 4;
    if (t < 5) {
        int target = b0 + t;
        int lo = 0, hi = NN;
        while (lo < hi) { int mid = (lo + hi) >> 1; if (seg[mid] < target) lo = mid + 1; else hi = mid; }
        sb[t] = lo;
        seg_start[target] = lo;   // p=511,t=4 -> seg_start[2048]=NN; overlaps write same value
    }
    __syncthreads();
    int w = t >> 6, l = t & 63;
    {
        int s = sb[w], e = sb[w + 1];
        float4 a0 = make_float4(0.f, 0.f, 0.f, 0.f), a1 = a0;
        int i = s;
        for (; i + 2 <= e; i += 2) {
            float4 v0 = *(const float4*)(ifeat + (size_t)i * D + l * 4);
            float4 v1 = *(const float4*)(ifeat + (size_t)(i + 1) * D + l * 4);
            a0.x += v0.x; a0.y += v0.y; a0.z += v0.z; a0.w += v0.w;
            a1.x += v1.x; a1.y += v1.y; a1.z += v1.z; a1.w += v1.w;
        }
        if (i < e) {
            float4 v0 = *(const float4*)(ifeat + (size_t)i * D + l * 4);
            a0.x += v0.x; a0.y += v0.y; a0.z += v0.z; a0.w += v0.w;
        }
        int cnt = e - s;
        float inv = 1.0f / (float)(cnt > 0 ? cnt : 1);
        float4 sm = make_float4((a0.x + a1.x) * inv, (a0.y + a1.y) * inv,
                                (a0.z + a1.z) * inv, (a0.w + a1.w) * inv);
        *(float4*)&anc[w][l * 4] = sm;
        *(float4*)(out + (size_t)(b0 + w) * 512 + 256 + l * 4) = sm;
    }
    __syncthreads();
    // feat_v: thread = output col t
    float a0 = 0.f, a1 = 0.f, a2 = 0.f, a3 = 0.f;
    const float* wrow = Wv + (size_t)t * D;
    for (int k = 0; k < D; k += 4) {
        float4 wv = *(const float4*)(wrow + k);
        a0 += anc[0][k] * wv.x + anc[0][k + 1] * wv.y + anc[0][k + 2] * wv.z + anc[0][k + 3] * wv.w;
        a1 += anc[1][k] * wv.x + anc[1][k + 1] * wv.y + anc[1][k + 2] * wv.z + anc[1][k + 3] * wv.w;
        a2 += anc[2][k] * wv.x + anc[2][k + 1] * wv.y + anc[2][k + 2] * wv.z + anc[2][k + 3] * wv.w;
        a3 += anc[3][k] * wv.x + anc[3][k + 1] * wv.y + anc[3][k + 2] * wv.z + anc[3][k + 3] * wv.w;
    }
    float bj = bv[t];
    feat_v[(size_t)(b0 + 0) * D + t] = a0 + bj;
    feat_v[(size_t)(b0 + 1) * D + t] = a1 + bj;
    feat_v[(size_t)(b0 + 2) * D + t] = a2 + bj;
    feat_v[(size_t)(b0 + 3) * D + t] = a3 + bj;
}

// K3 (MFMA, single-pass full-Wu): e[n] = we . sigmoid(bf16(ifeat[n]) @ bf16(Wu)^T + fv)
// 256 blocks x 1024 thr (16 waves/CU). FULL Wu in 128 KB LDS (swizzled).
// R12: 2-deep global A-prefetch (R11 lesson: neither ds nor HBM bound ->
// latency-bound; 1-deep covered ~350cyc vs ~300-900cyc load latency) +
// fast-rcp sigmoid. Rolled `#pragma unroll 1` loop (R8 lesson). acc -> AGPRs.
__global__ __launch_bounds__(1024, 4)
void k_attn_e_mfma(const float* __restrict__ ifeat, const float* __restrict__ Wu,
                   const float* __restrict__ feat_v, const float* __restrict__ we,
                   const int* __restrict__ seg_ids, float* __restrict__ e_out) {
    __shared__ __bf16 Bs[256 * 256];   // 128 KB; row j stride 512 B; byte ^= (j&7)<<4

    int tx = threadIdx.x;
    int lane = tx & 63;
    int w = tx >> 6;                   // 0..15
    int ln15 = lane & 15;
    int lg = lane >> 4;

    // ---- stage full Wu: thread -> (row jl=tx>>2, k-quarter kh=tx&3), 64 elems ----
    {
        int jl = tx >> 2, kh = tx & 3;
        const float* wp = Wu + (size_t)jl * D + kh * 64;
        char* rowp = (char*)Bs + jl * 512;
        int sw = (jl & 7) << 4;
#pragma unroll
        for (int q = 0; q < 8; ++q) {
            float4 b0 = *(const float4*)(wp + q * 8);
            float4 b1 = *(const float4*)(wp + q * 8 + 4);
            bf16x8 v;
            v[0] = (__bf16)b0.x; v[1] = (__bf16)b0.y; v[2] = (__bf16)b0.z; v[3] = (__bf16)b0.w;
            v[4] = (__bf16)b1.x; v[5] = (__bf16)b1.y; v[6] = (__bf16)b1.z; v[7] = (__bf16)b1.w;
            *(bf16x8*)(rowp + ((kh * 128 + q * 16) ^ sw)) = v;
        }
    }
    __syncthreads();

    int swr = (ln15 & 7) << 4;               // read swizzle (LDS row = ct*16+ln15, row&7==ln15&7)
    int klo = lg * 16;                       // k-byte offset of this lane-group's 8 elems
    const char* bbase = (const char*)Bs + ln15 * 512;
    const float* feph = feat_v + ln15;
    const float* weh  = we + ln15;

    int wgid = blockIdx.x * 16 + w;          // 0..4095

    for (int item = wgid; item < NN / 16; item += 4096) {
        int nb = item * 16;
        const float* ap = ifeat + (size_t)(nb + ln15) * D + lg * 8;

        f32x4 a0 = (f32x4){0.f,0.f,0.f,0.f}, a1 = a0, a2 = a0, a3 = a0,
              a4 = a0, a5 = a0, a6 = a0, a7 = a0,
              a8 = a0, a9 = a0, a10 = a0, a11 = a0,
              a12 = a0, a13 = a0, a14 = a0, a15 = a0;

        // rolled chunk loop, 2-deep named-register prefetch (all-static names)
        float4 xc = *(const float4*)(ap);
        float4 yc = *(const float4*)(ap + 4);
        float4 x1 = *(const float4*)(ap + 32);
        float4 y1 = *(const float4*)(ap + 36);
#pragma unroll 1
        for (int ch = 0; ch < 8; ++ch) {
            int nx = ((ch + 2) & 7) * 32;              // wrap: last 2 iters re-read ch0/1 (L2-hot)
            float4 x2 = *(const float4*)(ap + nx);
            float4 y2 = *(const float4*)(ap + nx + 4);
            bf16x8 af;
            af[0] = (__bf16)xc.x; af[1] = (__bf16)xc.y; af[2] = (__bf16)xc.z; af[3] = (__bf16)xc.w;
            af[4] = (__bf16)yc.x; af[5] = (__bf16)yc.y; af[6] = (__bf16)yc.z; af[7] = (__bf16)yc.w;
            int kb = (ch * 64 + klo) ^ swr;
            a0  = __builtin_amdgcn_mfma_f32_16x16x32_bf16(af, *(const bf16x8*)(bbase +  0 * 8192 + kb), a0,  0, 0, 0);
            a1  = __builtin_amdgcn_mfma_f32_16x16x32_bf16(af, *(const bf16x8*)(bbase +  1 * 8192 + kb), a1,  0, 0, 0);
            a2  = __builtin_amdgcn_mfma_f32_16x16x32_bf16(af, *(const bf16x8*)(bbase +  2 * 8192 + kb), a2,  0, 0, 0);
            a3  = __builtin_amdgcn_mfma_f32_16x16x32_bf16(af, *(const bf16x8*)(bbase +  3 * 8192 + kb), a3,  0, 0, 0);
            a4  = __builtin_amdgcn_mfma_f32_16x16x32_bf16(af, *(const bf16x8*)(bbase +  4 * 8192 + kb), a4,  0, 0, 0);
            a5  = __builtin_amdgcn_mfma_f32_16x16x32_bf16(af, *(const bf16x8*)(bbase +  5 * 8192 + kb), a5,  0, 0, 0);
            a6  = __builtin_amdgcn_mfma_f32_16x16x32_bf16(af, *(const bf16x8*)(bbase +  6 * 8192 + kb), a6,  0, 0, 0);
            a7  = __builtin_amdgcn_mfma_f32_16x16x32_bf16(af, *(const bf16x8*)(bbase +  7 * 8192 + kb), a7,  0, 0, 0);
            a8  = __builtin_amdgcn_mfma_f32_16x16x32_bf16(af, *(const bf16x8*)(bbase +  8 * 8192 + kb), a8,  0, 0, 0);
            a9  = __builtin_amdgcn_mfma_f32_16x16x32_bf16(af, *(const bf16x8*)(bbase +  9 * 8192 + kb), a9,  0, 0, 0);
            a10 = __builtin_amdgcn_mfma_f32_16x16x32_bf16(af, *(const bf16x8*)(bbase + 10 * 8192 + kb), a10, 0, 0, 0);
            a11 = __builtin_amdgcn_mfma_f32_16x16x32_bf16(af, *(const bf16x8*)(bbase + 11 * 8192 + kb), a11, 0, 0, 0);
            a12 = __builtin_amdgcn_mfma_f32_16x16x32_bf16(af, *(const bf16x8*)(bbase + 12 * 8192 + kb), a12, 0, 0, 0);
            a13 = __builtin_amdgcn_mfma_f32_16x16x32_bf16(af, *(const bf16x8*)(bbase + 13 * 8192 + kb), a13, 0, 0, 0);
            a14 = __builtin_amdgcn_mfma_f32_16x16x32_bf16(af, *(const bf16x8*)(bbase + 14 * 8192 + kb), a14, 0, 0, 0);
            a15 = __builtin_amdgcn_mfma_f32_16x16x32_bf16(af, *(const bf16x8*)(bbase + 15 * 8192 + kb), a15, 0, 0, 0);
            xc = x1; yc = y1; x1 = x2; y1 = y2;
        }

        // ---- epilogue: u = acc + feat_v[seg[row]][col]; part += we*sigmoid(u) ----
        int r0 = nb + lg * 4;
        const float* fp0 = feph + (size_t)seg_ids[r0 + 0] * D;
        const float* fp1 = feph + (size_t)seg_ids[r0 + 1] * D;
        const float* fp2 = feph + (size_t)seg_ids[r0 + 2] * D;
        const float* fp3 = feph + (size_t)seg_ids[r0 + 3] * D;
        float part0 = 0.f, part1 = 0.f, part2 = 0.f, part3 = 0.f;

#define EPI(AC, CT) { \
    float w_ = weh[(CT) * 16]; \
    part0 += w_ * __builtin_amdgcn_rcpf(1.f + __expf(-(AC[0] + fp0[(CT) * 16]))); \
    part1 += w_ * __builtin_amdgcn_rcpf(1.f + __expf(-(AC[1] + fp1[(CT) * 16]))); \
    part2 += w_ * __builtin_amdgcn_rcpf(1.f + __expf(-(AC[2] + fp2[(CT) * 16]))); \
    part3 += w_ * __builtin_amdgcn_rcpf(1.f + __expf(-(AC[3] + fp3[(CT) * 16]))); }

        EPI(a0, 0)  EPI(a1, 1)  EPI(a2, 2)  EPI(a3, 3)
        EPI(a4, 4)  EPI(a5, 5)  EPI(a6, 6)  EPI(a7, 7)
        EPI(a8, 8)  EPI(a9, 9)  EPI(a10, 10) EPI(a11, 11)
        EPI(a12, 12) EPI(a13, 13) EPI(a14, 14) EPI(a15, 15)
#undef EPI

        // reduce over the 16 col-lanes
#pragma unroll
        for (int off = 8; off >= 1; off >>= 1) {
            part0 += __shfl_xor(part0, off, 64);
            part1 += __shfl_xor(part1, off, 64);
            part2 += __shfl_xor(part2, off, 64);
            part3 += __shfl_xor(part3, off, 64);
        }
        if (ln15 == 0) {
            float4 o = make_float4(part0, part1, part2, part3);
            *(float4*)&e_out[r0] = o;
        }
    }
}

// K4: segment softmax + alpha-weighted segment sum -> out[:, 0:256]
__global__ void k_softmax_rst(const float* __restrict__ ifeat, const int* __restrict__ seg_start,
                              const float* __restrict__ e, float* __restrict__ out) {
    int b = blockIdx.x;
    int t = threadIdx.x; // 256
    int w = t >> 6, l = t & 63;
    int s = seg_start[b], en = seg_start[b + 1];
    float m = -1e30f;
    for (int i = s + t; i < en; i += 256) m = fmaxf(m, e[i]);
#pragma unroll
    for (int off = 32; off >= 1; off >>= 1) m = fmaxf(m, __shfl_xor(m, off, 64));
    __shared__ float red[4];
    if ((t & 63) == 0) red[t >> 6] = m;
    __syncthreads();
    float mall = fmaxf(fmaxf(red[0], red[1]), fmaxf(red[2], red[3]));
    float dsum = 0.f;
    for (int i = s + t; i < en; i += 256) dsum += __expf(e[i] - mall);
#pragma unroll
    for (int off = 32; off >= 1; off >>= 1) dsum += __shfl_xor(dsum, off, 64);
    __shared__ float red2[4];
    if ((t & 63) == 0) red2[t >> 6] = dsum;
    __syncthreads();
    float denom = red2[0] + red2[1] + red2[2] + red2[3];
    float invd = (en > s) ? 1.0f / denom : 0.f;

    // phase 3: wave-per-row float4 weighted sum
    float4 acc = make_float4(0.f, 0.f, 0.f, 0.f);
    for (int i = s + w; i < en; i += 4) {
        float al = __expf(e[i] - mall) * invd;   // broadcast load + per-lane exp
        float4 v = *(const float4*)(ifeat + (size_t)i * D + l * 4);
        acc.x += v.x * al; acc.y += v.y * al; acc.z += v.z * al; acc.w += v.w * al;
    }
    __shared__ float red3[4][256];
    *(float4*)&red3[w][l * 4] = acc;
    __syncthreads();
    out[(size_t)b * 512 + t] = (red3[0][t] + red3[1][t]) + (red3[2][t] + red3[3][t]);
}

extern "C" void kernel_launch(void* const* d_in, const int* in_sizes, int n_in,
                              void* d_out, int out_size, void* d_ws, size_t ws_size,
                              hipStream_t stream) {
    const float* ifeat = (const float*)d_in[0];
    const float* Wu    = (const float*)d_in[1];
    const float* Wv    = (const float*)d_in[2];
    const float* bv    = (const float*)d_in[3];
    const float* we    = (const float*)d_in[4];
    const int*   seg   = (const int*)d_in[5];
    float* out = (float*)d_out;

    char* ws = (char*)d_ws;
    int*   seg_start = (int*)ws;                                   // (B+1) ints
    float* feat_v    = (float*)(ws + 16384);                       // B*D floats (2 MB)
    float* e_buf     = (float*)(ws + 16384 + (size_t)B * D * 4);   // NN floats (400 KB)

    k_prep<<<B / 4, 256, 0, stream>>>(ifeat, seg, Wv, bv, out, seg_start, feat_v);
    k_attn_e_mfma<<<256, 1024, 0, stream>>>(ifeat, Wu, feat_v, we, seg, e_buf);
    k_softmax_rst<<<B, 256, 0, stream>>>(ifeat, seg_start, e_buf, out);
}